// Round 1
// baseline (5766.945 us; speedup 1.0000x reference)
//
#include <hip/hip_runtime.h>

// Problem constants (shapes fixed by the reference)
#define DIM   256      // IN_DIM == OUT_DIM
#define NHEAD 8
#define HDIM  32
// SCALE = sqrt(32); we multiply by 1/sqrt(32)
#define RSCALE 0.17677669529663687f

// ---------- small helpers ----------
__device__ __forceinline__ float bf2f(unsigned short u) {
    return __uint_as_float(((unsigned)u) << 16);
}
__device__ __forceinline__ unsigned short f2bf(float f) {
    unsigned u = __float_as_uint(f);
    u += 0x7FFFu + ((u >> 16) & 1u);   // round-to-nearest-even
    return (unsigned short)(u >> 16);
}

// ---------------------------------------------------------------------------
// Kernel 1: build fused weights.
// Wcat_p [256][1024] = [Wk_p | Wv_p | Wq_p@R_writes | Wq_p@R_cites]
// Wcat_a [256][768]  = [Wk_a | Wv_a | Wq_a@R_writtenby]
// (per-head fold: WqR[i, h*32+f] = sum_d Wq[i, h*32+d] * R[h, d, f]), plus biases.
// ---------------------------------------------------------------------------
__global__ __launch_bounds__(256) void prep_weights(
    const float* __restrict__ Wk_p, const float* __restrict__ Wv_p, const float* __restrict__ Wq_p,
    const float* __restrict__ R_w,  const float* __restrict__ R_c,
    const float* __restrict__ bk_p, const float* __restrict__ bv_p, const float* __restrict__ bq_p,
    const float* __restrict__ Wk_a, const float* __restrict__ Wv_a, const float* __restrict__ Wq_a,
    const float* __restrict__ R_wb,
    const float* __restrict__ bk_a, const float* __restrict__ bv_a, const float* __restrict__ bq_a,
    float* __restrict__ Wcat_p, float* __restrict__ bcat_p,
    float* __restrict__ Wcat_a, float* __restrict__ bcat_a)
{
    const int WP = 256 * 1024, WA = 256 * 768;
    int tid = blockIdx.x * 256 + threadIdx.x;
    if (tid < WP) {
        int k = tid >> 10, c = tid & 1023;
        float v;
        if (c < 256)       v = Wk_p[k * 256 + c];
        else if (c < 512)  v = Wv_p[k * 256 + (c - 256)];
        else {
            int f = c & 255;
            const float* R = (c < 768) ? R_w : R_c;
            int h = f >> 5, fd = f & 31;
            float s = 0.f;
            #pragma unroll
            for (int d = 0; d < 32; d++) s += Wq_p[k * 256 + h * 32 + d] * R[(h * 32 + d) * 32 + fd];
            v = s;
        }
        Wcat_p[tid] = v;
    } else if (tid < WP + WA) {
        int t2 = tid - WP;
        int k = t2 / 768, c = t2 - k * 768;
        float v;
        if (c < 256)       v = Wk_a[k * 256 + c];
        else if (c < 512)  v = Wv_a[k * 256 + (c - 256)];
        else {
            int f = c - 512, h = f >> 5, fd = f & 31;
            float s = 0.f;
            #pragma unroll
            for (int d = 0; d < 32; d++) s += Wq_a[k * 256 + h * 32 + d] * R_wb[(h * 32 + d) * 32 + fd];
            v = s;
        }
        Wcat_a[t2] = v;
    } else if (tid < WP + WA + 1024) {
        int c = tid - WP - WA;
        float v;
        if (c < 256)       v = bk_p[c];
        else if (c < 512)  v = bv_p[c - 256];
        else {
            int f = c & 255;
            const float* R = (c < 768) ? R_w : R_c;
            int h = f >> 5, fd = f & 31;
            float s = 0.f;
            #pragma unroll
            for (int d = 0; d < 32; d++) s += bq_p[h * 32 + d] * R[(h * 32 + d) * 32 + fd];
            v = s;
        }
        bcat_p[c] = v;
    } else if (tid < WP + WA + 1024 + 768) {
        int c = tid - WP - WA - 1024;
        float v;
        if (c < 256)       v = bk_a[c];
        else if (c < 512)  v = bv_a[c - 256];
        else {
            int f = c - 512, h = f >> 5, fd = f & 31;
            float s = 0.f;
            #pragma unroll
            for (int d = 0; d < 32; d++) s += bq_a[h * 32 + d] * R_wb[(h * 32 + d) * 32 + fd];
            v = s;
        }
        bcat_a[c] = v;
    }
}

// ---------------------------------------------------------------------------
// Kernel 2: Y[bf16] = X[f32, N x 256] @ W[f32, 256 x ncols] + bias.
// 64x64 tile per 256-thread block, K chunked by 64, 4x4 micro-tile/thread.
// ---------------------------------------------------------------------------
__global__ __launch_bounds__(256) void gemm_bias_bf16(
    const float* __restrict__ X, const float* __restrict__ W, const float* __restrict__ bias,
    unsigned short* __restrict__ Y, int nrows, int ncols)
{
    __shared__ float Xs[64][68];  // [kk][r]   (transposed stage)
    __shared__ float Ws[64][68];  // [kk][c]
    const int t  = threadIdx.x;
    const int tx = t & 15, ty = t >> 4;
    const int row0 = blockIdx.y * 64;
    const int col0 = blockIdx.x * 64;

    float acc[4][4] = {};

    for (int k0 = 0; k0 < 256; k0 += 64) {
        #pragma unroll
        for (int i = 0; i < 4; i++) {
            int idx = t + i * 256;          // 0..1023 float4 slots
            int r = idx >> 4;               // 0..63
            int kq = idx & 15;              // float4 index along k
            float4 v = make_float4(0.f, 0.f, 0.f, 0.f);
            if (row0 + r < nrows)
                v = *(const float4*)&X[(size_t)(row0 + r) * 256 + k0 + kq * 4];
            Xs[kq * 4 + 0][r] = v.x; Xs[kq * 4 + 1][r] = v.y;
            Xs[kq * 4 + 2][r] = v.z; Xs[kq * 4 + 3][r] = v.w;
        }
        #pragma unroll
        for (int i = 0; i < 4; i++) {
            int idx = t + i * 256;
            int kk = idx >> 4;
            int cq = idx & 15;
            float4 v = *(const float4*)&W[(size_t)(k0 + kk) * ncols + col0 + cq * 4];
            *(float4*)&Ws[kk][cq * 4] = v;
        }
        __syncthreads();
        #pragma unroll 16
        for (int kk = 0; kk < 64; kk++) {
            float4 a = *(const float4*)&Xs[kk][ty * 4];
            float4 b = *(const float4*)&Ws[kk][tx * 4];
            float av[4] = {a.x, a.y, a.z, a.w};
            float bv[4] = {b.x, b.y, b.z, b.w};
            #pragma unroll
            for (int i = 0; i < 4; i++)
                #pragma unroll
                for (int j = 0; j < 4; j++)
                    acc[i][j] += av[i] * bv[j];
        }
        __syncthreads();
    }

    float bj[4];
    #pragma unroll
    for (int j = 0; j < 4; j++) bj[j] = bias[col0 + tx * 4 + j];
    #pragma unroll
    for (int i = 0; i < 4; i++) {
        int r = row0 + ty * 4 + i;
        if (r < nrows) {
            union { ushort4 u4; unsigned short s[4]; } pk;
            #pragma unroll
            for (int j = 0; j < 4; j++) pk.s[j] = f2bf(acc[i][j] + bj[j]);
            *(ushort4*)&Y[(size_t)r * ncols + col0 + tx * 4] = pk.u4;
        }
    }
}

// ---------------------------------------------------------------------------
// Kernel 3: edge message passing. One wave (64 lanes) per edge.
// Lane l handles elements l*4..l*4+3 of the 256-dim row (head = l>>3).
// score_h = dot(QR[dst], K[src]) over head h / sqrt(32); a = exp(clip(score));
// accum[dst] += v * a (per-head); norm[dst] += mean_h(a).
// ---------------------------------------------------------------------------
__global__ __launch_bounds__(256) void edge_kernel(
    const unsigned short* __restrict__ Ysrc, int src_stride, int k_off, int v_off,
    const unsigned short* __restrict__ Ydst, int dst_stride, int q_off,
    const int* __restrict__ ei, int E,
    float* __restrict__ accum, float* __restrict__ normv)
{
    const int wave = threadIdx.x >> 6, lane = threadIdx.x & 63;
    const int e = blockIdx.x * 4 + wave;
    if (e >= E) return;
    const int src = ei[e];
    const int dst = ei[E + e];

    const ushort4 qu = *(const ushort4*)&Ydst[(size_t)dst * dst_stride + q_off + lane * 4];
    const ushort4 ku = *(const ushort4*)&Ysrc[(size_t)src * src_stride + k_off + lane * 4];
    const ushort4 vu = *(const ushort4*)&Ysrc[(size_t)src * src_stride + v_off + lane * 4];

    float partial = bf2f(qu.x) * bf2f(ku.x) + bf2f(qu.y) * bf2f(ku.y)
                  + bf2f(qu.z) * bf2f(ku.z) + bf2f(qu.w) * bf2f(ku.w);
    // reduce within the 8-lane head group
    partial += __shfl_xor(partial, 1);
    partial += __shfl_xor(partial, 2);
    partial += __shfl_xor(partial, 4);

    float score = partial * RSCALE;
    score = fminf(fmaxf(score, -5.f), 5.f);
    const float a = expf(score);

    // sum of the 8 per-head a's (one representative per group via bits 3..5)
    float hsum = a;
    hsum += __shfl_xor(hsum, 8);
    hsum += __shfl_xor(hsum, 16);
    hsum += __shfl_xor(hsum, 32);

    float* ap = accum + (size_t)dst * 256 + lane * 4;
    atomicAdd(ap + 0, bf2f(vu.x) * a);
    atomicAdd(ap + 1, bf2f(vu.y) * a);
    atomicAdd(ap + 2, bf2f(vu.z) * a);
    atomicAdd(ap + 3, bf2f(vu.w) * a);
    if (lane == 0) atomicAdd(normv + dst, hsum * 0.125f);
}

// ---------------------------------------------------------------------------
// Kernel 4: epilogue. 16 rows per 256-thread block, in place over d_out.
// agg = accum / clip(norm); y = agg @ Wo + bo + x; out = LN(y) * g + be.
// ---------------------------------------------------------------------------
__global__ __launch_bounds__(256) void epilogue_kernel(
    float* __restrict__ accum_out, const float* __restrict__ normv,
    const float* __restrict__ x, const float* __restrict__ Wo,
    const float* __restrict__ bo, const float* __restrict__ g, const float* __restrict__ be,
    int nrows)
{
    __shared__ float s_agg[16][256];
    __shared__ float s_y[16][256];
    const int t = threadIdx.x;
    const int row0 = blockIdx.x * 16;

    #pragma unroll
    for (int i = 0; i < 16; i++) {
        int r = row0 + i;
        float v = 0.f;
        if (r < nrows) v = accum_out[(size_t)r * 256 + t] / fmaxf(normv[r], 1e-8f);
        s_agg[i][t] = v;
    }
    __syncthreads();

    float acc[16];
    const float bc = bo[t];
    #pragma unroll
    for (int i = 0; i < 16; i++) acc[i] = bc;

    for (int k = 0; k < 256; k += 4) {
        float w0 = Wo[(size_t)(k + 0) * 256 + t];
        float w1 = Wo[(size_t)(k + 1) * 256 + t];
        float w2 = Wo[(size_t)(k + 2) * 256 + t];
        float w3 = Wo[(size_t)(k + 3) * 256 + t];
        #pragma unroll
        for (int i = 0; i < 16; i++) {
            float4 a = *(const float4*)&s_agg[i][k];
            acc[i] += a.x * w0 + a.y * w1 + a.z * w2 + a.w * w3;
        }
    }

    #pragma unroll
    for (int i = 0; i < 16; i++) {
        int r = row0 + i;
        float xv = (r < nrows) ? x[(size_t)r * 256 + t] : 0.f;
        s_y[i][t] = acc[i] + xv;
    }
    __syncthreads();

    const int wave = t >> 6, lane = t & 63;
    #pragma unroll
    for (int ii = 0; ii < 4; ii++) {
        int i = wave * 4 + ii;
        int r = row0 + i;
        float4 y = *(const float4*)&s_y[i][lane * 4];
        float sum = y.x + y.y + y.z + y.w;
        for (int o = 1; o < 64; o <<= 1) sum += __shfl_xor(sum, o);
        float m = sum * (1.f / 256.f);
        float d0 = y.x - m, d1 = y.y - m, d2 = y.z - m, d3 = y.w - m;
        float vs = d0 * d0 + d1 * d1 + d2 * d2 + d3 * d3;
        for (int o = 1; o < 64; o <<= 1) vs += __shfl_xor(vs, o);
        float rstd = rsqrtf(vs * (1.f / 256.f) + 1e-5f);
        if (r < nrows) {
            float4 gv  = *(const float4*)&g[lane * 4];
            float4 bev = *(const float4*)&be[lane * 4];
            float4 o4;
            o4.x = d0 * rstd * gv.x + bev.x;
            o4.y = d1 * rstd * gv.y + bev.y;
            o4.z = d2 * rstd * gv.z + bev.z;
            o4.w = d3 * rstd * gv.w + bev.w;
            *(float4*)&accum_out[(size_t)r * 256 + lane * 4] = o4;
        }
    }
}

// ---------------------------------------------------------------------------
extern "C" void kernel_launch(void* const* d_in, const int* in_sizes, int n_in,
                              void* d_out, int out_size, void* d_ws, size_t ws_size,
                              hipStream_t stream)
{
    const float* x_p  = (const float*)d_in[0];
    const float* x_a  = (const float*)d_in[1];
    const float* Wk_p = (const float*)d_in[2];
    const float* bk_p = (const float*)d_in[3];
    const float* Wq_p = (const float*)d_in[4];
    const float* bq_p = (const float*)d_in[5];
    const float* Wv_p = (const float*)d_in[6];
    const float* bv_p = (const float*)d_in[7];
    const float* Wo_p = (const float*)d_in[8];
    const float* bo_p = (const float*)d_in[9];
    const float* g_p  = (const float*)d_in[10];
    const float* be_p = (const float*)d_in[11];
    const float* Wk_a = (const float*)d_in[12];
    const float* bk_a = (const float*)d_in[13];
    const float* Wq_a = (const float*)d_in[14];
    const float* bq_a = (const float*)d_in[15];
    const float* Wv_a = (const float*)d_in[16];
    const float* bv_a = (const float*)d_in[17];
    const float* Wo_a = (const float*)d_in[18];
    const float* bo_a = (const float*)d_in[19];
    const float* g_a  = (const float*)d_in[20];
    const float* be_a = (const float*)d_in[21];
    const float* R_w  = (const float*)d_in[22];
    const int*   ei_w = (const int*)d_in[23];
    const float* R_c  = (const float*)d_in[24];
    const int*   ei_c = (const int*)d_in[25];
    const float* R_wb = (const float*)d_in[26];
    const int*   ei_wb= (const int*)d_in[27];

    const int N   = in_sizes[0] / 256;
    const int Ew  = in_sizes[23] / 2;
    const int Ec  = in_sizes[25] / 2;
    const int Ewb = in_sizes[27] / 2;

    // workspace layout (256B aligned): ~361 MB total
    size_t off = 0;
    auto walloc = [&](size_t bytes) {
        void* p = (char*)d_ws + off;
        off += (bytes + 255) & ~(size_t)255;
        return p;
    };
    float* Wcat_p = (float*)walloc((size_t)256 * 1024 * sizeof(float));
    float* bcat_p = (float*)walloc(1024 * sizeof(float));
    float* Wcat_a = (float*)walloc((size_t)256 * 768 * sizeof(float));
    float* bcat_a = (float*)walloc(768 * sizeof(float));
    unsigned short* Y_p = (unsigned short*)walloc((size_t)N * 1024 * sizeof(unsigned short));
    unsigned short* Y_a = (unsigned short*)walloc((size_t)N * 768  * sizeof(unsigned short));
    float* norms  = (float*)walloc((size_t)2 * N * sizeof(float));
    float* norm_p = norms;
    float* norm_a = norms + N;

    float* accum_p = (float*)d_out;                      // reuse output as accumulator
    float* accum_a = (float*)d_out + (size_t)N * 256;

    hipMemsetAsync(d_out, 0, (size_t)2 * N * 256 * sizeof(float), stream);
    hipMemsetAsync(norms, 0, (size_t)2 * N * sizeof(float), stream);

    {
        int total = 256 * 1024 + 256 * 768 + 1024 + 768;
        prep_weights<<<(total + 255) / 256, 256, 0, stream>>>(
            Wk_p, Wv_p, Wq_p, R_w, R_c, bk_p, bv_p, bq_p,
            Wk_a, Wv_a, Wq_a, R_wb, bk_a, bv_a, bq_a,
            Wcat_p, bcat_p, Wcat_a, bcat_a);
    }

    gemm_bias_bf16<<<dim3(1024 / 64, (N + 63) / 64), 256, 0, stream>>>(x_p, Wcat_p, bcat_p, Y_p, N, 1024);
    gemm_bias_bf16<<<dim3(768 / 64,  (N + 63) / 64), 256, 0, stream>>>(x_a, Wcat_a, bcat_a, Y_a, N, 768);

    // writes: author -> paper   (K,V from Y_a; QR_writes at col 512 of Y_p)
    edge_kernel<<<(Ew + 3) / 4, 256, 0, stream>>>(Y_a, 768, 0, 256, Y_p, 1024, 512, ei_w, Ew, accum_p, norm_p);
    // cites: paper -> paper     (K,V from Y_p; QR_cites at col 768 of Y_p)
    edge_kernel<<<(Ec + 3) / 4, 256, 0, stream>>>(Y_p, 1024, 0, 256, Y_p, 1024, 768, ei_c, Ec, accum_p, norm_p);
    // writtenby: paper -> author (K,V from Y_p; QR_writtenby at col 512 of Y_a)
    edge_kernel<<<(Ewb + 3) / 4, 256, 0, stream>>>(Y_p, 1024, 0, 256, Y_a, 768, 512, ei_wb, Ewb, accum_a, norm_a);

    epilogue_kernel<<<(N + 15) / 16, 256, 0, stream>>>(accum_p, norm_p, x_p, Wo_p, bo_p, g_p, be_p, N);
    epilogue_kernel<<<(N + 15) / 16, 256, 0, stream>>>(accum_a, norm_a, x_a, Wo_a, bo_a, g_a, be_a, N);
}

// Round 2
// 1810.434 us; speedup vs baseline: 3.1854x; 3.1854x over previous
//
#include <hip/hip_runtime.h>

#define RSCALE 0.17677669529663687f   // 1/sqrt(32)

typedef __attribute__((ext_vector_type(8))) short bf16x8;
typedef __attribute__((ext_vector_type(4))) float f32x4;

__device__ __forceinline__ float bf2f(unsigned short u) {
    return __uint_as_float(((unsigned)u) << 16);
}
__device__ __forceinline__ unsigned short f2bf(float f) {
    unsigned u = __float_as_uint(f);
    u += 0x7FFFu + ((u >> 16) & 1u);   // round-to-nearest-even
    return (unsigned short)(u >> 16);
}

// ---------------------------------------------------------------------------
// Kernel 1: fused weights, TRANSPOSED + bf16 for the MFMA GEMM.
// Wt_p [1024][256] bf16 : rows = [Wk_p | Wv_p | Wq_p@R_writes | Wq_p@R_cites]^T
// Wt_a [768][256]  bf16 : rows = [Wk_a | Wv_a | Wq_a@R_writtenby]^T
// bcat_* stay f32.
// ---------------------------------------------------------------------------
__global__ __launch_bounds__(256) void prep_weights(
    const float* __restrict__ Wk_p, const float* __restrict__ Wv_p, const float* __restrict__ Wq_p,
    const float* __restrict__ R_w,  const float* __restrict__ R_c,
    const float* __restrict__ bk_p, const float* __restrict__ bv_p, const float* __restrict__ bq_p,
    const float* __restrict__ Wk_a, const float* __restrict__ Wv_a, const float* __restrict__ Wq_a,
    const float* __restrict__ R_wb,
    const float* __restrict__ bk_a, const float* __restrict__ bv_a, const float* __restrict__ bq_a,
    unsigned short* __restrict__ Wt_p, float* __restrict__ bcat_p,
    unsigned short* __restrict__ Wt_a, float* __restrict__ bcat_a)
{
    const int WP = 1024 * 256, WA = 768 * 256;
    int tid = blockIdx.x * 256 + threadIdx.x;
    if (tid < WP) {
        int c = tid >> 8, k = tid & 255;
        float v;
        if (c < 256)       v = Wk_p[k * 256 + c];
        else if (c < 512)  v = Wv_p[k * 256 + (c - 256)];
        else {
            int f = c & 255;
            const float* R = (c < 768) ? R_w : R_c;
            int h = f >> 5, fd = f & 31;
            float s = 0.f;
            #pragma unroll
            for (int d = 0; d < 32; d++) s += Wq_p[k * 256 + h * 32 + d] * R[(h * 32 + d) * 32 + fd];
            v = s;
        }
        Wt_p[tid] = f2bf(v);
    } else if (tid < WP + WA) {
        int t2 = tid - WP;
        int c = t2 >> 8, k = t2 & 255;
        float v;
        if (c < 256)       v = Wk_a[k * 256 + c];
        else if (c < 512)  v = Wv_a[k * 256 + (c - 256)];
        else {
            int f = c - 512, h = f >> 5, fd = f & 31;
            float s = 0.f;
            #pragma unroll
            for (int d = 0; d < 32; d++) s += Wq_a[k * 256 + h * 32 + d] * R_wb[(h * 32 + d) * 32 + fd];
            v = s;
        }
        Wt_a[t2] = f2bf(v);
    } else if (tid < WP + WA + 1024) {
        int c = tid - WP - WA;
        float v;
        if (c < 256)       v = bk_p[c];
        else if (c < 512)  v = bv_p[c - 256];
        else {
            int f = c & 255;
            const float* R = (c < 768) ? R_w : R_c;
            int h = f >> 5, fd = f & 31;
            float s = 0.f;
            #pragma unroll
            for (int d = 0; d < 32; d++) s += bq_p[h * 32 + d] * R[(h * 32 + d) * 32 + fd];
            v = s;
        }
        bcat_p[c] = v;
    } else if (tid < WP + WA + 1024 + 768) {
        int c = tid - WP - WA - 1024;
        float v;
        if (c < 256)       v = bk_a[c];
        else if (c < 512)  v = bv_a[c - 256];
        else {
            int f = c - 512, h = f >> 5, fd = f & 31;
            float s = 0.f;
            #pragma unroll
            for (int d = 0; d < 32; d++) s += bq_a[h * 32 + d] * R_wb[(h * 32 + d) * 32 + fd];
            v = s;
        }
        bcat_a[c] = v;
    }
}

// ---------------------------------------------------------------------------
// Kernel 2: MFMA GEMM.  Y[bf16, nrows x ncols] = X[f32] @ Wt^T + bias.
// Block 256 = 4 waves in 2x2; each wave 64x64 via 4x4 tiles of 16x16x32 bf16.
// BK=64, K=256. LDS rows padded +8 bf16 (16 B) -> b128 frag reads are
// 2-way-bank-aliased only (free per m136), and 16 B alignment is kept.
// ---------------------------------------------------------------------------
__global__ __launch_bounds__(256) void gemm_mfma(
    const float* __restrict__ X, const unsigned short* __restrict__ Wt,
    const float* __restrict__ bias, unsigned short* __restrict__ Y,
    int nrows, int ncols)
{
    __shared__ unsigned short As[128][72];
    __shared__ unsigned short Bs[128][72];
    const int t = threadIdx.x;
    const int wave = t >> 6, lane = t & 63;
    const int wm = wave >> 1, wn = wave & 1;
    const int row0 = blockIdx.y * 128, col0 = blockIdx.x * 128;
    const int lquad = lane >> 4, lmod = lane & 15;

    f32x4 acc[4][4];
    #pragma unroll
    for (int i = 0; i < 4; i++)
        #pragma unroll
        for (int j = 0; j < 4; j++) acc[i][j] = (f32x4){0.f, 0.f, 0.f, 0.f};

    for (int k0 = 0; k0 < 256; k0 += 64) {
        // stage A: 128 rows x 64 f32 -> bf16 (convert in flight)
        #pragma unroll
        for (int p = 0; p < 8; p++) {
            int r = p * 16 + (t >> 4);
            int c4 = (t & 15) * 4;
            float4 v = make_float4(0.f, 0.f, 0.f, 0.f);
            if (row0 + r < nrows) v = *(const float4*)&X[(size_t)(row0 + r) * 256 + k0 + c4];
            ushort4 pk;
            pk.x = f2bf(v.x); pk.y = f2bf(v.y); pk.z = f2bf(v.z); pk.w = f2bf(v.w);
            *(ushort4*)&As[r][c4] = pk;
        }
        // stage B: 128 rows of Wt x 64 bf16 (16B per thread per pass)
        #pragma unroll
        for (int p = 0; p < 4; p++) {
            int r = p * 32 + (t >> 3);
            int c8 = (t & 7) * 8;
            float4 w = *(const float4*)&Wt[(size_t)(col0 + r) * 256 + k0 + c8];
            *(float4*)&Bs[r][c8] = w;
        }
        __syncthreads();
        #pragma unroll
        for (int ks = 0; ks < 2; ks++) {
            bf16x8 af[4], bfr[4];
            #pragma unroll
            for (int i = 0; i < 4; i++)
                af[i] = *(const bf16x8*)&As[wm * 64 + i * 16 + lmod][ks * 32 + lquad * 8];
            #pragma unroll
            for (int j = 0; j < 4; j++)
                bfr[j] = *(const bf16x8*)&Bs[wn * 64 + j * 16 + lmod][ks * 32 + lquad * 8];
            #pragma unroll
            for (int i = 0; i < 4; i++)
                #pragma unroll
                for (int j = 0; j < 4; j++)
                    acc[i][j] = __builtin_amdgcn_mfma_f32_16x16x32_bf16(af[i], bfr[j], acc[i][j], 0, 0, 0);
        }
        __syncthreads();
    }

    // C/D layout: col = lane&15, row = (lane>>4)*4 + reg  (m89-verified)
    float bj[4];
    #pragma unroll
    for (int j = 0; j < 4; j++) bj[j] = bias[col0 + wn * 64 + j * 16 + lmod];
    #pragma unroll
    for (int i = 0; i < 4; i++) {
        int rbase = row0 + wm * 64 + i * 16 + lquad * 4;
        #pragma unroll
        for (int rg = 0; rg < 4; rg++) {
            int r = rbase + rg;
            if (r < nrows) {
                #pragma unroll
                for (int j = 0; j < 4; j++) {
                    int c = col0 + wn * 64 + j * 16 + lmod;
                    Y[(size_t)r * ncols + c] = f2bf(acc[i][j][rg] + bj[j]);
                }
            }
        }
    }
}

// ---------------------------------------------------------------------------
// CSR build: histogram -> 3-kernel exclusive scan -> scatter with cursors.
// ---------------------------------------------------------------------------
__global__ __launch_bounds__(256) void hist_kernel(const int* __restrict__ ei, int E,
                                                   int* __restrict__ cnt)
{
    int i = blockIdx.x * 256 + threadIdx.x;
    if (i < E) atomicAdd(&cnt[ei[E + i]], 1);
}

__global__ __launch_bounds__(256) void scan1(const int* __restrict__ cnt, int n,
                                             int* __restrict__ bsum)
{
    __shared__ int s[256];
    int b = blockIdx.x, t = threadIdx.x;
    int i0 = b * 1024 + t * 4, v = 0;
    if (i0 + 3 < n) {
        int4 q = *(const int4*)&cnt[i0];
        v = q.x + q.y + q.z + q.w;
    } else {
        for (int j = 0; j < 4; j++) if (i0 + j < n) v += cnt[i0 + j];
    }
    s[t] = v; __syncthreads();
    for (int off = 128; off > 0; off >>= 1) {
        if (t < off) s[t] += s[t + off];
        __syncthreads();
    }
    if (t == 0) bsum[b] = s[0];
}

__global__ __launch_bounds__(256) void scan2(int* __restrict__ bsum, int nb)
{
    __shared__ int s[256];
    int t = threadIdx.x;
    int v = (t < nb) ? bsum[t] : 0;
    s[t] = v; __syncthreads();
    for (int off = 1; off < 256; off <<= 1) {
        int x = 0;
        if (t >= off) x = s[t - off];
        __syncthreads();
        s[t] += x;
        __syncthreads();
    }
    if (t < nb) bsum[t] = s[t] - v;   // exclusive
}

// cnt is overwritten with the cursor (== row_ptr) to save workspace.
__global__ __launch_bounds__(256) void scan3(int* __restrict__ cnt, int n,
                                             const int* __restrict__ bsum,
                                             int* __restrict__ row_ptr)
{
    __shared__ int s[256];
    int b = blockIdx.x, t = threadIdx.x;
    int i0 = b * 1024 + t * 4;
    int v[4]; int tot = 0;
    #pragma unroll
    for (int j = 0; j < 4; j++) { v[j] = (i0 + j < n) ? cnt[i0 + j] : 0; tot += v[j]; }
    s[t] = tot; __syncthreads();
    for (int off = 1; off < 256; off <<= 1) {
        int x = 0;
        if (t >= off) x = s[t - off];
        __syncthreads();
        s[t] += x;
        __syncthreads();
    }
    int run = s[t] - tot + bsum[b];
    #pragma unroll
    for (int j = 0; j < 4; j++) {
        int i = i0 + j;
        if (i < n) {
            row_ptr[i] = run;
            cnt[i] = run;      // cursor
            run += v[j];
            if (i == n - 1) row_ptr[n] = run;
        }
    }
}

__global__ __launch_bounds__(256) void scatter_kernel(const int* __restrict__ ei, int E, int rel,
                                                      int* __restrict__ cursor, int* __restrict__ eout)
{
    int i = blockIdx.x * 256 + threadIdx.x;
    if (i < E) {
        int pos = atomicAdd(&cursor[ei[E + i]], 1);
        eout[pos] = (ei[i] << 1) | rel;
    }
}

// ---------------------------------------------------------------------------
// Kernel 3: per-node gather-reduce. One wave per dst node; lane l owns dims
// l*4..l*4+3 (head = l>>3). For each incoming edge: score = <Q_rel, K_src>
// reduced within the 8-lane head group; accumulate V_src * exp(clip) in regs.
// ONE coalesced float4 row-write per node (no atomics).
// ---------------------------------------------------------------------------
__global__ __launch_bounds__(256) void aggregate_kernel(
    const unsigned short* __restrict__ Ydst, int dstride, int qoff0, int qoff1,
    const unsigned short* __restrict__ Ysrc0, int sstride0,
    const unsigned short* __restrict__ Ysrc1, int sstride1,
    const int* __restrict__ row_ptr, const int* __restrict__ edges,
    int nnodes, float* __restrict__ accum, float* __restrict__ normv)
{
    const int wave = threadIdx.x >> 6, lane = threadIdx.x & 63;
    const int node = blockIdx.x * 4 + wave;
    if (node >= nnodes) return;

    const ushort4 q0u = *(const ushort4*)&Ydst[(size_t)node * dstride + qoff0 + lane * 4];
    const ushort4 q1u = *(const ushort4*)&Ydst[(size_t)node * dstride + qoff1 + lane * 4];
    const float q0x = bf2f(q0u.x), q0y = bf2f(q0u.y), q0z = bf2f(q0u.z), q0w = bf2f(q0u.w);
    const float q1x = bf2f(q1u.x), q1y = bf2f(q1u.y), q1z = bf2f(q1u.z), q1w = bf2f(q1u.w);

    float a0 = 0.f, a1 = 0.f, a2 = 0.f, a3 = 0.f, hs = 0.f;
    const int beg = row_ptr[node], end = row_ptr[node + 1];
    for (int i = beg; i < end; i++) {
        const int e = edges[i];
        const int rel = e & 1;
        const size_t src = (size_t)(e >> 1);
        const unsigned short* Ys = rel ? Ysrc1 : Ysrc0;
        const int ss = rel ? sstride1 : sstride0;
        const ushort4 ku = *(const ushort4*)&Ys[src * ss + lane * 4];
        const ushort4 vu = *(const ushort4*)&Ys[src * ss + 256 + lane * 4];
        float p = (rel ? q1x : q0x) * bf2f(ku.x) + (rel ? q1y : q0y) * bf2f(ku.y)
                + (rel ? q1z : q0z) * bf2f(ku.z) + (rel ? q1w : q0w) * bf2f(ku.w);
        p += __shfl_xor(p, 1);
        p += __shfl_xor(p, 2);
        p += __shfl_xor(p, 4);
        float sc = fminf(fmaxf(p * RSCALE, -5.f), 5.f);
        float a = expf(sc);
        a0 += bf2f(vu.x) * a;
        a1 += bf2f(vu.y) * a;
        a2 += bf2f(vu.z) * a;
        a3 += bf2f(vu.w) * a;
        hs += a;
    }
    // sum the 8 distinct per-head values (lanes within a group are equal)
    hs += __shfl_xor(hs, 8);
    hs += __shfl_xor(hs, 16);
    hs += __shfl_xor(hs, 32);

    float4 o = make_float4(a0, a1, a2, a3);
    *(float4*)&accum[(size_t)node * 256 + lane * 4] = o;
    if (lane == 0) normv[node] = hs * 0.125f;
}

// ---------------------------------------------------------------------------
// Kernel 4: epilogue (unchanged from round 1).
// ---------------------------------------------------------------------------
__global__ __launch_bounds__(256) void epilogue_kernel(
    float* __restrict__ accum_out, const float* __restrict__ normv,
    const float* __restrict__ x, const float* __restrict__ Wo,
    const float* __restrict__ bo, const float* __restrict__ g, const float* __restrict__ be,
    int nrows)
{
    __shared__ float s_agg[16][256];
    __shared__ float s_y[16][256];
    const int t = threadIdx.x;
    const int row0 = blockIdx.x * 16;

    #pragma unroll
    for (int i = 0; i < 16; i++) {
        int r = row0 + i;
        float v = 0.f;
        if (r < nrows) v = accum_out[(size_t)r * 256 + t] / fmaxf(normv[r], 1e-8f);
        s_agg[i][t] = v;
    }
    __syncthreads();

    float acc[16];
    const float bc = bo[t];
    #pragma unroll
    for (int i = 0; i < 16; i++) acc[i] = bc;

    for (int k = 0; k < 256; k += 4) {
        float w0 = Wo[(size_t)(k + 0) * 256 + t];
        float w1 = Wo[(size_t)(k + 1) * 256 + t];
        float w2 = Wo[(size_t)(k + 2) * 256 + t];
        float w3 = Wo[(size_t)(k + 3) * 256 + t];
        #pragma unroll
        for (int i = 0; i < 16; i++) {
            float4 a = *(const float4*)&s_agg[i][k];
            acc[i] += a.x * w0 + a.y * w1 + a.z * w2 + a.w * w3;
        }
    }

    #pragma unroll
    for (int i = 0; i < 16; i++) {
        int r = row0 + i;
        float xv = (r < nrows) ? x[(size_t)r * 256 + t] : 0.f;
        s_y[i][t] = acc[i] + xv;
    }
    __syncthreads();

    const int wave = t >> 6, lane = t & 63;
    #pragma unroll
    for (int ii = 0; ii < 4; ii++) {
        int i = wave * 4 + ii;
        int r = row0 + i;
        float4 y = *(const float4*)&s_y[i][lane * 4];
        float sum = y.x + y.y + y.z + y.w;
        for (int o = 1; o < 64; o <<= 1) sum += __shfl_xor(sum, o);
        float m = sum * (1.f / 256.f);
        float d0 = y.x - m, d1 = y.y - m, d2 = y.z - m, d3 = y.w - m;
        float vs = d0 * d0 + d1 * d1 + d2 * d2 + d3 * d3;
        for (int o = 1; o < 64; o <<= 1) vs += __shfl_xor(vs, o);
        float rstd = rsqrtf(vs * (1.f / 256.f) + 1e-5f);
        if (r < nrows) {
            float4 gv  = *(const float4*)&g[lane * 4];
            float4 bev = *(const float4*)&be[lane * 4];
            float4 o4;
            o4.x = d0 * rstd * gv.x + bev.x;
            o4.y = d1 * rstd * gv.y + bev.y;
            o4.z = d2 * rstd * gv.z + bev.z;
            o4.w = d3 * rstd * gv.w + bev.w;
            *(float4*)&accum_out[(size_t)r * 256 + lane * 4] = o4;
        }
    }
}

// ---------------------------------------------------------------------------
extern "C" void kernel_launch(void* const* d_in, const int* in_sizes, int n_in,
                              void* d_out, int out_size, void* d_ws, size_t ws_size,
                              hipStream_t stream)
{
    const float* x_p  = (const float*)d_in[0];
    const float* x_a  = (const float*)d_in[1];
    const float* Wk_p = (const float*)d_in[2];
    const float* bk_p = (const float*)d_in[3];
    const float* Wq_p = (const float*)d_in[4];
    const float* bq_p = (const float*)d_in[5];
    const float* Wv_p = (const float*)d_in[6];
    const float* bv_p = (const float*)d_in[7];
    const float* Wo_p = (const float*)d_in[8];
    const float* bo_p = (const float*)d_in[9];
    const float* g_p  = (const float*)d_in[10];
    const float* be_p = (const float*)d_in[11];
    const float* Wk_a = (const float*)d_in[12];
    const float* bk_a = (const float*)d_in[13];
    const float* Wq_a = (const float*)d_in[14];
    const float* bq_a = (const float*)d_in[15];
    const float* Wv_a = (const float*)d_in[16];
    const float* bv_a = (const float*)d_in[17];
    const float* Wo_a = (const float*)d_in[18];
    const float* bo_a = (const float*)d_in[19];
    const float* g_a  = (const float*)d_in[20];
    const float* be_a = (const float*)d_in[21];
    const float* R_w  = (const float*)d_in[22];
    const int*   ei_w = (const int*)d_in[23];
    const float* R_c  = (const float*)d_in[24];
    const int*   ei_c = (const int*)d_in[25];
    const float* R_wb = (const float*)d_in[26];
    const int*   ei_wb= (const int*)d_in[27];

    const int N   = in_sizes[0] / 256;
    const int Ew  = in_sizes[23] / 2;
    const int Ec  = in_sizes[25] / 2;
    const int Ewb = in_sizes[27] / 2;

    size_t off = 0;
    auto walloc = [&](size_t bytes) {
        void* p = (char*)d_ws + off;
        off += (bytes + 255) & ~(size_t)255;
        return p;
    };
    unsigned short* Wt_p = (unsigned short*)walloc((size_t)1024 * 256 * 2);
    unsigned short* Wt_a = (unsigned short*)walloc((size_t)768 * 256 * 2);
    float* bcat_p = (float*)walloc(1024 * 4);
    float* bcat_a = (float*)walloc(768 * 4);
    unsigned short* Y_p = (unsigned short*)walloc((size_t)N * 1024 * 2);
    unsigned short* Y_a = (unsigned short*)walloc((size_t)N * 768 * 2);
    float* norms  = (float*)walloc((size_t)2 * N * 4);
    float* norm_p = norms;
    float* norm_a = norms + N;
    int* cnt_p = (int*)walloc((size_t)N * 4);        // histogram -> cursor
    int* rp_p  = (int*)walloc((size_t)(N + 1) * 4);
    int* e_p   = (int*)walloc((size_t)(Ew + Ec) * 4);
    int* cnt_a = (int*)walloc((size_t)N * 4);
    int* rp_a  = (int*)walloc((size_t)(N + 1) * 4);
    int* e_a   = (int*)walloc((size_t)Ewb * 4);
    int* bsum  = (int*)walloc(1024 * 4);

    float* accum_p = (float*)d_out;
    float* accum_a = (float*)d_out + (size_t)N * 256;

    const int nb = (N + 1023) / 1024;   // scan blocks (98 for N=100k)

    hipMemsetAsync(cnt_p, 0, (size_t)N * 4, stream);
    hipMemsetAsync(cnt_a, 0, (size_t)N * 4, stream);

    {
        int total = 1024 * 256 + 768 * 256 + 1024 + 768;
        prep_weights<<<(total + 255) / 256, 256, 0, stream>>>(
            Wk_p, Wv_p, Wq_p, R_w, R_c, bk_p, bv_p, bq_p,
            Wk_a, Wv_a, Wq_a, R_wb, bk_a, bv_a, bq_a,
            Wt_p, bcat_p, Wt_a, bcat_a);
    }

    // histograms (independent of GEMMs)
    hist_kernel<<<(Ew + 255) / 256, 256, 0, stream>>>(ei_w, Ew, cnt_p);
    hist_kernel<<<(Ec + 255) / 256, 256, 0, stream>>>(ei_c, Ec, cnt_p);
    hist_kernel<<<(Ewb + 255) / 256, 256, 0, stream>>>(ei_wb, Ewb, cnt_a);

    // projections (MFMA)
    gemm_mfma<<<dim3(1024 / 128, (N + 127) / 128), 256, 0, stream>>>(x_p, Wt_p, bcat_p, Y_p, N, 1024);
    gemm_mfma<<<dim3(768 / 128,  (N + 127) / 128), 256, 0, stream>>>(x_a, Wt_a, bcat_a, Y_a, N, 768);

    // CSR: papers
    scan1<<<nb, 256, 0, stream>>>(cnt_p, N, bsum);
    scan2<<<1, 256, 0, stream>>>(bsum, nb);
    scan3<<<nb, 256, 0, stream>>>(cnt_p, N, bsum, rp_p);
    scatter_kernel<<<(Ew + 255) / 256, 256, 0, stream>>>(ei_w, Ew, 0, cnt_p, e_p);
    scatter_kernel<<<(Ec + 255) / 256, 256, 0, stream>>>(ei_c, Ec, 1, cnt_p, e_p);
    // CSR: authors
    scan1<<<nb, 256, 0, stream>>>(cnt_a, N, bsum);
    scan2<<<1, 256, 0, stream>>>(bsum, nb);
    scan3<<<nb, 256, 0, stream>>>(cnt_a, N, bsum, rp_a);
    scatter_kernel<<<(Ewb + 255) / 256, 256, 0, stream>>>(ei_wb, Ewb, 0, cnt_a, e_a);

    // aggregate: papers receive writes(rel0, src=author) + cites(rel1, src=paper)
    aggregate_kernel<<<(N + 3) / 4, 256, 0, stream>>>(
        Y_p, 1024, 512, 768, Y_a, 768, Y_p, 1024, rp_p, e_p, N, accum_p, norm_p);
    // authors receive writtenby(rel0, src=paper); Q at col 512 of Y_a
    aggregate_kernel<<<(N + 3) / 4, 256, 0, stream>>>(
        Y_a, 768, 512, 512, Y_p, 1024, Y_p, 1024, rp_a, e_a, N, accum_a, norm_a);

    epilogue_kernel<<<(N + 15) / 16, 256, 0, stream>>>(accum_p, norm_p, x_p, Wo_p, bo_p, g_p, be_p, N);
    epilogue_kernel<<<(N + 15) / 16, 256, 0, stream>>>(accum_a, norm_a, x_a, Wo_a, bo_a, g_a, be_a, N);
}